// Round 3
// baseline (364.255 us; speedup 1.0000x reference)
//
#include <hip/hip_runtime.h>
#include <hip/hip_bf16.h>

#define M_DIM 8192
#define K_DIM 2048
#define N_DIM 4096
#define NGROUP 32
#define EPSV 1e-5f
#define NKT (K_DIM / 64)

typedef __bf16 bf16x8 __attribute__((ext_vector_type(8)));
typedef float floatx4 __attribute__((ext_vector_type(4)));

__device__ __forceinline__ void g2lds16(const void* g, void* l) {
    __builtin_amdgcn_global_load_lds(
        (__attribute__((address_space(1))) void*)(uintptr_t)g,
        (__attribute__((address_space(3))) void*)(uint32_t)(uintptr_t)l,
        16, 0, 0);
}

// ---------------- kernel 1: fp32 -> bf16 cast of x and W ----------------
__global__ __launch_bounds__(256) void convert_bf16(
    const float* __restrict__ x, const float* __restrict__ w,
    __bf16* __restrict__ xb, __bf16* __restrict__ wb)
{
    const size_t nx = (size_t)M_DIM * K_DIM / 8;
    const size_t nw = (size_t)N_DIM * K_DIM / 8;
    size_t i = (size_t)blockIdx.x * 256 + threadIdx.x;
    const float4* src;
    bf16x8* dst;
    size_t j;
    if (i < nx) { src = (const float4*)x; dst = (bf16x8*)xb; j = i; }
    else if (i < nx + nw) { src = (const float4*)w; dst = (bf16x8*)wb; j = i - nx; }
    else return;
    float4 a = src[j * 2];
    float4 b = src[j * 2 + 1];
    bf16x8 o = { (__bf16)a.x, (__bf16)a.y, (__bf16)a.z, (__bf16)a.w,
                 (__bf16)b.x, (__bf16)b.y, (__bf16)b.z, (__bf16)b.w };
    dst[j] = o;
}

// ---- kernel 2: 256x256 8-phase bf16 MFMA GEMM fused with GroupNorm + group-min ----
// R7: fix R6's gate stall. R6 issued the last prefetch loads in phase 2 and
// gated vmcnt at the next tile top — waiting on loads only ~1 phase (~150 cyc)
// old, far under L2/HBM latency; with 1 block/CU (128 KiB LDS) every wave
// froze at the gate each tile (MfmaUtil 38%, +1700 cyc/tile vs the ~4000-cyc
// serial floor). R7 issues ALL 8 prefetch loads at the tile top, right after
// the gate: issue->wait distance = full tile (~4000 cyc) > HBM latency, so
// the vmcnt(0) gate only ever waits on OLD loads (the T4 substance). Phase
// skeleton (ds_read | barrier | lgkm | setprio MFMA | barrier) unchanged.
__global__ __launch_bounds__(512, 2) void gemm_gn_min(
    const __bf16* __restrict__ xb, const __bf16* __restrict__ wb,
    const float* __restrict__ bg, const float* __restrict__ gamma,
    const float* __restrict__ beta, float* __restrict__ gmin)
{
    __shared__ __bf16 lA[2][256 * 64];   // 64 KiB
    __shared__ __bf16 lB[2][256 * 64];   // 64 KiB

    const int t = threadIdx.x;
    const int m0 = blockIdx.x * 256;
    const int n0 = blockIdx.y * 256;
    const int w  = t >> 6;        // wave 0..7
    const int wr = w >> 2;        // 0..1  (row half)
    const int wc = w & 3;         // 0..3  (col quarter, 64 cols each)
    const int l  = t & 63;
    const int quad = l >> 4;
    const int r  = l & 15;
    const int r7 = r & 7;

    // staging: 512 threads cover 64 rows x 8 chunks per round; 4 rounds each
    // for the 256-row A and B tiles. round stride 64 rows keeps (row&7) and
    // hence the swizzle invariant.
    const int rowS = t >> 3;          // 0..63
    const int cS   = t & 7;
    const int cSw  = cS ^ (rowS & 7); // swizzled global chunk
    const __bf16* gA = xb + (size_t)(m0 + rowS) * K_DIM + cSw * 8;
    const __bf16* gB = wb + (size_t)(n0 + rowS) * K_DIM + cSw * 8;
    const int sOff = rowS * 64 + cS * 8;   // linear LDS dest (elements)

    // fragment read bases (swizzled on the read side, same XOR)
    const int aBase = (wr * 128 + r) * 64;
    const int bBase = (wc * 64  + r) * 64;
    const int ck0 = (quad ^ r7) * 8;        // ks=0 chunk offset (elements)
    const int ck1 = ((4 + quad) ^ r7) * 8;  // ks=1

    floatx4 acc[8][4];
    #pragma unroll
    for (int i = 0; i < 8; ++i)
        #pragma unroll
        for (int j = 0; j < 4; ++j)
            acc[i][j] = (floatx4){0.f, 0.f, 0.f, 0.f};

#define SA(BUF, KK, J) g2lds16(gA + (KK) + (size_t)((J) * 64) * K_DIM, \
                               (void*)&lA[BUF][(J) * 4096 + sOff])
#define SB(BUF, KK, J) g2lds16(gB + (KK) + (size_t)((J) * 64) * K_DIM, \
                               (void*)&lB[BUF][(J) * 4096 + sOff])

#define PH_PRE  __builtin_amdgcn_sched_barrier(0);                        \
                __builtin_amdgcn_s_barrier();                             \
                asm volatile("s_waitcnt lgkmcnt(0)" ::: "memory");        \
                __builtin_amdgcn_sched_barrier(0);                        \
                __builtin_amdgcn_s_setprio(1);
#define PH_POST __builtin_amdgcn_s_setprio(0);                            \
                __builtin_amdgcn_sched_barrier(0);                        \
                __builtin_amdgcn_s_barrier();

#define TILE_STEP(C, KT, PF)                                                   \
  do {                                                                         \
    /* gate: all outstanding loads are THIS tile's, issued a full tile ago */  \
    asm volatile("s_waitcnt vmcnt(0)" ::: "memory");                           \
    __builtin_amdgcn_sched_barrier(0);                                         \
    __builtin_amdgcn_s_barrier();                                              \
    __builtin_amdgcn_sched_barrier(0);                                         \
    const int kn_ = ((KT) + 1) * 64;                                           \
    if (PF) {  /* issue ALL next-tile loads now: max issue->wait distance */   \
      SA(1 - (C), kn_, 0); SA(1 - (C), kn_, 1);                                \
      SA(1 - (C), kn_, 2); SA(1 - (C), kn_, 3);                                \
      SB(1 - (C), kn_, 0); SB(1 - (C), kn_, 1);                                \
      SB(1 - (C), kn_, 2); SB(1 - (C), kn_, 3);                                \
    } else { (void)kn_; }                                                      \
    __builtin_amdgcn_sched_barrier(0);                                         \
    bf16x8 af[4][2], b0[2][2], b1[2][2];                                       \
    /* ---- phase 0: read A-half0 (mt 0..3) + B-half0 (nt 0..1) ---- */        \
    _Pragma("unroll")                                                          \
    for (int mt = 0; mt < 4; ++mt) {                                           \
      af[mt][0] = *(const bf16x8*)&lA[C][aBase + mt * 1024 + ck0];             \
      af[mt][1] = *(const bf16x8*)&lA[C][aBase + mt * 1024 + ck1];             \
    }                                                                          \
    _Pragma("unroll")                                                          \
    for (int nt = 0; nt < 2; ++nt) {                                           \
      b0[nt][0] = *(const bf16x8*)&lB[C][bBase + nt * 1024 + ck0];             \
      b0[nt][1] = *(const bf16x8*)&lB[C][bBase + nt * 1024 + ck1];             \
    }                                                                          \
    PH_PRE                                                                     \
    _Pragma("unroll")                                                          \
    for (int mt = 0; mt < 4; ++mt)                                             \
      _Pragma("unroll")                                                        \
      for (int nt = 0; nt < 2; ++nt)                                           \
        _Pragma("unroll")                                                      \
        for (int ks = 0; ks < 2; ++ks)                                         \
          acc[mt][nt] = __builtin_amdgcn_mfma_f32_16x16x32_bf16(               \
              af[mt][ks], b0[nt][ks], acc[mt][nt], 0, 0, 0);                   \
    PH_POST                                                                    \
    /* ---- phase 1: read B-half1 (nt 2..3) ---- */                            \
    _Pragma("unroll")                                                          \
    for (int nt = 0; nt < 2; ++nt) {                                           \
      b1[nt][0] = *(const bf16x8*)&lB[C][bBase + (nt + 2) * 1024 + ck0];       \
      b1[nt][1] = *(const bf16x8*)&lB[C][bBase + (nt + 2) * 1024 + ck1];       \
    }                                                                          \
    PH_PRE                                                                     \
    _Pragma("unroll")                                                          \
    for (int mt = 0; mt < 4; ++mt)                                             \
      _Pragma("unroll")                                                        \
      for (int nt = 0; nt < 2; ++nt)                                           \
        _Pragma("unroll")                                                      \
        for (int ks = 0; ks < 2; ++ks)                                         \
          acc[mt][nt + 2] = __builtin_amdgcn_mfma_f32_16x16x32_bf16(           \
              af[mt][ks], b1[nt][ks], acc[mt][nt + 2], 0, 0, 0);               \
    PH_POST                                                                    \
    /* ---- phase 2: reload A-half1 (mt 4..7), B-half0 still live ---- */      \
    _Pragma("unroll")                                                          \
    for (int mt = 0; mt < 4; ++mt) {                                           \
      af[mt][0] = *(const bf16x8*)&lA[C][aBase + (mt + 4) * 1024 + ck0];       \
      af[mt][1] = *(const bf16x8*)&lA[C][aBase + (mt + 4) * 1024 + ck1];       \
    }                                                                          \
    PH_PRE                                                                     \
    _Pragma("unroll")                                                          \
    for (int mt = 0; mt < 4; ++mt)                                             \
      _Pragma("unroll")                                                        \
      for (int nt = 0; nt < 2; ++nt)                                           \
        _Pragma("unroll")                                                      \
        for (int ks = 0; ks < 2; ++ks)                                         \
          acc[mt + 4][nt] = __builtin_amdgcn_mfma_f32_16x16x32_bf16(           \
              af[mt][ks], b0[nt][ks], acc[mt + 4][nt], 0, 0, 0);               \
    PH_POST                                                                    \
    /* ---- phase 3: A-half1 x B-half1, registers only ---- */                 \
    PH_PRE                                                                     \
    _Pragma("unroll")                                                          \
    for (int mt = 0; mt < 4; ++mt)                                             \
      _Pragma("unroll")                                                        \
      for (int nt = 0; nt < 2; ++nt)                                           \
        _Pragma("unroll")                                                      \
        for (int ks = 0; ks < 2; ++ks)                                         \
          acc[mt + 4][nt + 2] = __builtin_amdgcn_mfma_f32_16x16x32_bf16(       \
              af[mt][ks], b1[nt][ks], acc[mt + 4][nt + 2], 0, 0, 0);           \
    PH_POST                                                                    \
  } while (0)

    // prologue: stage tile 0 into buf 0 (8 loads/thread); first gate absorbs
    // the one-time full latency.
    SA(0, 0, 0); SA(0, 0, 1); SA(0, 0, 2); SA(0, 0, 3);
    SB(0, 0, 0); SB(0, 0, 1); SB(0, 0, 2); SB(0, 0, 3);

    #pragma unroll 1
    for (int kt2 = 0; kt2 < NKT / 2 - 1; ++kt2) {
        TILE_STEP(0, 2 * kt2, true);
        TILE_STEP(1, 2 * kt2 + 1, true);
    }
    TILE_STEP(0, NKT - 2, true);
    TILE_STEP(1, NKT - 1, false);

    // ---- epilogue: + b_gemm, GroupNorm over 128-col groups, group-min ----
    // C/D layout (verified m89/m91): col = lane&15, row = (lane>>4)*4 + reg.
    // Wave covers 64 cols = half a group; partner wave is wc^1. Exchange
    // (sum, sumsq) then per-row mins through LDS scratch (lA is dead).
    float bgv[4], gv[4], bv[4];
    #pragma unroll
    for (int nt = 0; nt < 4; ++nt) {
        int cg = n0 + wc * 64 + nt * 16 + r;
        bgv[nt] = bg[cg];
        gv[nt]  = gamma[cg];
        bv[nt]  = beta[cg];
    }

    float* sc1 = (float*)&lA[0][0];   // [2 wr][128 row][4 wc][2] = 8 KiB
    float* sc2 = sc1 + 2048;          // [2 wr][128 row][4 wc]    = 4 KiB

    // stage 1: per-row partial (sum, sumsq) over this wave's 64 cols
    #pragma unroll
    for (int mt = 0; mt < 8; ++mt) {
        #pragma unroll
        for (int reg = 0; reg < 4; ++reg) {
            int rowH = mt * 16 + quad * 4 + reg;     // 0..127 within wr half
            float s = 0.f, ss = 0.f;
            #pragma unroll
            for (int nt = 0; nt < 4; ++nt) {
                float y = acc[mt][nt][reg] + bgv[nt];
                s += y;
                ss += y * y;
            }
            #pragma unroll
            for (int d = 1; d < 16; d <<= 1) {       // reduce 16 lanes of quad
                s  += __shfl_xor(s,  d, 64);
                ss += __shfl_xor(ss, d, 64);
            }
            if (r == 0) {
                int idx = ((wr * 128 + rowH) * 4 + wc) * 2;
                sc1[idx] = s;
                sc1[idx + 1] = ss;
            }
        }
    }
    __syncthreads();

    // stage 2: full-group stats (own + partner), normalize, per-wave min
    #pragma unroll
    for (int mt = 0; mt < 8; ++mt) {
        #pragma unroll
        for (int reg = 0; reg < 4; ++reg) {
            int rowH = mt * 16 + quad * 4 + reg;
            int ib = (wr * 128 + rowH) * 4;
            float s  = sc1[(ib + wc) * 2]     + sc1[(ib + (wc ^ 1)) * 2];
            float ss = sc1[(ib + wc) * 2 + 1] + sc1[(ib + (wc ^ 1)) * 2 + 1];
            float mean = s * (1.0f / 128.0f);
            float var  = ss * (1.0f / 128.0f) - mean * mean;
            float rstd = rsqrtf(var + EPSV);
            float mn = 1e30f;
            #pragma unroll
            for (int nt = 0; nt < 4; ++nt) {
                float y = acc[mt][nt][reg] + bgv[nt];
                float z = (y - mean) * rstd * gv[nt] + bv[nt];
                mn = fminf(mn, z);
            }
            #pragma unroll
            for (int d = 1; d < 16; d <<= 1)
                mn = fminf(mn, __shfl_xor(mn, d, 64));
            if (r == 0) sc2[ib + wc] = mn;
        }
    }
    __syncthreads();

    // stage 3: combine the two waves of each group, write gmin
    if ((wc & 1) == 0 && r == 0) {
        #pragma unroll
        for (int mt = 0; mt < 8; ++mt) {
            #pragma unroll
            for (int reg = 0; reg < 4; ++reg) {
                int rowH = mt * 16 + quad * 4 + reg;
                int ib = (wr * 128 + rowH) * 4;
                float mn = fminf(sc2[ib + wc], sc2[ib + wc + 1]);
                int R = m0 + wr * 128 + rowH;
                gmin[(size_t)R * NGROUP + blockIdx.y * 2 + (wc >> 1)] = mn;
            }
        }
    }
#undef SA
#undef SB
#undef PH_PRE
#undef PH_POST
#undef TILE_STEP
}

// ---------------- kernel 3: rowmin over groups + broadcast bias ----------------
__global__ __launch_bounds__(256) void finalize(
    const float* __restrict__ gmin, const float* __restrict__ bias,
    float* __restrict__ out)
{
    const int m = blockIdx.x;
    const int t = threadIdx.x;
    float v = gmin[(size_t)m * NGROUP + (t & 31)];
    #pragma unroll
    for (int d = 1; d < 32; d <<= 1)
        v = fminf(v, __shfl_xor(v, d, 64));
    float4* out4 = (float4*)(out + (size_t)m * N_DIM);
    const float4* bias4 = (const float4*)bias;
    for (int i = t; i < N_DIM / 4; i += 256) {
        float4 b = bias4[i];
        out4[i] = make_float4(v + b.x, v + b.y, v + b.z, v + b.w);
    }
}

extern "C" void kernel_launch(void* const* d_in, const int* in_sizes, int n_in,
                              void* d_out, int out_size, void* d_ws, size_t ws_size,
                              hipStream_t stream)
{
    const float* x     = (const float*)d_in[0];
    const float* W     = (const float*)d_in[1];
    const float* bg    = (const float*)d_in[2];
    const float* gamma = (const float*)d_in[3];
    const float* beta  = (const float*)d_in[4];
    const float* bias  = (const float*)d_in[5];
    float* out = (float*)d_out;

    // ws layout: xb (32 MiB bf16) | wb (16 MiB bf16) | gmin (1 MiB fp32)
    __bf16* xb = (__bf16*)d_ws;
    __bf16* wb = xb + (size_t)M_DIM * K_DIM;
    float* gmin = (float*)(wb + (size_t)N_DIM * K_DIM);

    size_t ntot8 = ((size_t)M_DIM * K_DIM + (size_t)N_DIM * K_DIM) / 8;
    int cvt_blocks = (int)((ntot8 + 255) / 256);
    convert_bf16<<<cvt_blocks, 256, 0, stream>>>(x, W, xb, wb);

    dim3 grid(M_DIM / 256, N_DIM / 256);
    gemm_gn_min<<<grid, 512, 0, stream>>>(xb, wb, bg, gamma, beta, gmin);

    finalize<<<M_DIM, 256, 0, stream>>>(gmin, bias, out);
}

// Round 4
// 355.084 us; speedup vs baseline: 1.0258x; 1.0258x over previous
//
#include <hip/hip_runtime.h>
#include <hip/hip_bf16.h>

#define M_DIM 8192
#define K_DIM 2048
#define N_DIM 4096
#define NGROUP 32
#define EPSV 1e-5f
#define NKT (K_DIM / 64)

typedef __bf16 bf16x8 __attribute__((ext_vector_type(8)));
typedef float floatx4 __attribute__((ext_vector_type(4)));

__device__ __forceinline__ void g2lds16(const void* g, void* l) {
    __builtin_amdgcn_global_load_lds(
        (__attribute__((address_space(1))) void*)(uintptr_t)g,
        (__attribute__((address_space(3))) void*)(uint32_t)(uintptr_t)l,
        16, 0, 0);
}

// ---------------- kernel 1: fp32 -> bf16 cast of x and W ----------------
__global__ __launch_bounds__(256) void convert_bf16(
    const float* __restrict__ x, const float* __restrict__ w,
    __bf16* __restrict__ xb, __bf16* __restrict__ wb)
{
    const size_t nx = (size_t)M_DIM * K_DIM / 8;
    const size_t nw = (size_t)N_DIM * K_DIM / 8;
    size_t i = (size_t)blockIdx.x * 256 + threadIdx.x;
    const float4* src;
    bf16x8* dst;
    size_t j;
    if (i < nx) { src = (const float4*)x; dst = (bf16x8*)xb; j = i; }
    else if (i < nx + nw) { src = (const float4*)w; dst = (bf16x8*)wb; j = i - nx; }
    else return;
    float4 a = src[j * 2];
    float4 b = src[j * 2 + 1];
    bf16x8 o = { (__bf16)a.x, (__bf16)a.y, (__bf16)a.z, (__bf16)a.w,
                 (__bf16)b.x, (__bf16)b.y, (__bf16)b.z, (__bf16)b.w };
    dst[j] = o;
}

// ---- kernel 2: 256x256 double-buffered bf16 MFMA GEMM + GroupNorm + group-min ----
// R8: post-mortem of R6/R7 (36-38% MfmaUtil): the phase schedule's NINE
// block-wide barriers per K-tile at 1 block/CU cost ~1500-2200 cyc/tile of
// sync/skew with nothing resident to cover it. R8 = T3's MINIMUM 2-phase
// recipe: explicit LDS double-buffer, stage tile t+1 BEFORE computing tile t,
// exactly ONE __syncthreads() per K-step (its implicit vmcnt(0) drain only
// ever waits on loads issued a full compute-phase earlier). No inline asm in
// the loop: compiler schedules ds_read/MFMA with fine-grained lgkmcnt (m97),
// which my sched_barrier(0) pinning in R6/R7 was defeating (m141).
// Geometry unchanged from R6/R7: BM=BN=256, BK=64, 512 thr = 8 waves (2Mx4N),
// per-wave 128x64 output (acc[8][4]), chunk-XOR swizzle via pre-swizzled
// global source (conflict-free, measured 0).
__global__ __launch_bounds__(512, 2) void gemm_gn_min(
    const __bf16* __restrict__ xb, const __bf16* __restrict__ wb,
    const float* __restrict__ bg, const float* __restrict__ gamma,
    const float* __restrict__ beta, float* __restrict__ gmin)
{
    __shared__ __bf16 lA[2][256 * 64];   // 64 KiB
    __shared__ __bf16 lB[2][256 * 64];   // 64 KiB

    const int t = threadIdx.x;
    const int m0 = blockIdx.x * 256;
    const int n0 = blockIdx.y * 256;
    const int w  = t >> 6;        // wave 0..7
    const int wr = w >> 2;        // 0..1  (row half)
    const int wc = w & 3;         // 0..3  (col quarter, 64 cols each)
    const int l  = t & 63;
    const int quad = l >> 4;
    const int r  = l & 15;
    const int r7 = r & 7;

    // staging: 512 threads cover 64 rows x 8 chunks per round; 4 rounds each
    // for the 256-row A and B tiles. Round stride 64 rows keeps (row & 7) and
    // hence the swizzle invariant.
    const int rowS = t >> 3;          // 0..63
    const int cS   = t & 7;
    const int cSw  = cS ^ (rowS & 7); // swizzled global chunk
    const __bf16* gA = xb + (size_t)(m0 + rowS) * K_DIM + cSw * 8;
    const __bf16* gB = wb + (size_t)(n0 + rowS) * K_DIM + cSw * 8;
    const int sOff = rowS * 64 + cS * 8;   // linear LDS dest (elements)

    // fragment read bases (swizzled on the read side, same XOR)
    const int aBase = (wr * 128 + r) * 64;
    const int bBase = (wc * 64  + r) * 64;
    const int ck0 = (quad ^ r7) * 8;        // ks=0 chunk offset (elements)
    const int ck1 = ((4 + quad) ^ r7) * 8;  // ks=1

    floatx4 acc[8][4];
    #pragma unroll
    for (int i = 0; i < 8; ++i)
        #pragma unroll
        for (int j = 0; j < 4; ++j)
            acc[i][j] = (floatx4){0.f, 0.f, 0.f, 0.f};

#define STAGE(BUF, KK)                                                         \
  do {                                                                         \
    _Pragma("unroll")                                                          \
    for (int j_ = 0; j_ < 4; ++j_)                                             \
      g2lds16(gA + (KK) + (size_t)(j_ * 64) * K_DIM,                           \
              (void*)&lA[BUF][j_ * 4096 + sOff]);                              \
    _Pragma("unroll")                                                          \
    for (int j_ = 0; j_ < 4; ++j_)                                             \
      g2lds16(gB + (KK) + (size_t)(j_ * 64) * K_DIM,                           \
              (void*)&lB[BUF][j_ * 4096 + sOff]);                              \
  } while (0)

// Compute one BK=64 K-tile from buffer C. Two A-halves to bound live regs
// (peak ~192: acc 128 + af 32 + b0/b1 32). Compiler inserts lgkmcnt waits.
#define COMPUTE(C)                                                             \
  do {                                                                         \
    bf16x8 af[4][2], b0[2][2], b1[2][2];                                       \
    _Pragma("unroll")                                                          \
    for (int mt = 0; mt < 4; ++mt) {                                           \
      af[mt][0] = *(const bf16x8*)&lA[C][aBase + mt * 1024 + ck0];             \
      af[mt][1] = *(const bf16x8*)&lA[C][aBase + mt * 1024 + ck1];             \
    }                                                                          \
    _Pragma("unroll")                                                          \
    for (int nt = 0; nt < 2; ++nt) {                                           \
      b0[nt][0] = *(const bf16x8*)&lB[C][bBase + nt * 1024 + ck0];             \
      b0[nt][1] = *(const bf16x8*)&lB[C][bBase + nt * 1024 + ck1];             \
      b1[nt][0] = *(const bf16x8*)&lB[C][bBase + (nt + 2) * 1024 + ck0];       \
      b1[nt][1] = *(const bf16x8*)&lB[C][bBase + (nt + 2) * 1024 + ck1];       \
    }                                                                          \
    _Pragma("unroll")                                                          \
    for (int mt = 0; mt < 4; ++mt)                                             \
      _Pragma("unroll")                                                        \
      for (int nt = 0; nt < 2; ++nt)                                           \
        _Pragma("unroll")                                                      \
        for (int ks = 0; ks < 2; ++ks) {                                       \
          acc[mt][nt] = __builtin_amdgcn_mfma_f32_16x16x32_bf16(               \
              af[mt][ks], b0[nt][ks], acc[mt][nt], 0, 0, 0);                   \
          acc[mt][nt + 2] = __builtin_amdgcn_mfma_f32_16x16x32_bf16(           \
              af[mt][ks], b1[nt][ks], acc[mt][nt + 2], 0, 0, 0);               \
        }                                                                      \
    _Pragma("unroll")                                                          \
    for (int mt = 0; mt < 4; ++mt) {                                           \
      af[mt][0] = *(const bf16x8*)&lA[C][aBase + (mt + 4) * 1024 + ck0];       \
      af[mt][1] = *(const bf16x8*)&lA[C][aBase + (mt + 4) * 1024 + ck1];       \
    }                                                                          \
    _Pragma("unroll")                                                          \
    for (int mt = 0; mt < 4; ++mt)                                             \
      _Pragma("unroll")                                                        \
      for (int nt = 0; nt < 2; ++nt)                                           \
        _Pragma("unroll")                                                      \
        for (int ks = 0; ks < 2; ++ks) {                                       \
          acc[mt + 4][nt] = __builtin_amdgcn_mfma_f32_16x16x32_bf16(           \
              af[mt][ks], b0[nt][ks], acc[mt + 4][nt], 0, 0, 0);               \
          acc[mt + 4][nt + 2] = __builtin_amdgcn_mfma_f32_16x16x32_bf16(       \
              af[mt][ks], b1[nt][ks], acc[mt + 4][nt + 2], 0, 0, 0);           \
        }                                                                      \
  } while (0)

// One K-step: prefetch next tile into the other buffer, compute current,
// single barrier (implicit vmcnt(0)+lgkmcnt(0) drain — the staged loads were
// issued one full compute-phase ago, so the drain waits on OLD loads only).
#define STEP(C, KT, PF)                                                        \
  do {                                                                         \
    if (PF) STAGE(1 - (C), ((KT) + 1) * 64);                                   \
    COMPUTE(C);                                                                \
    __syncthreads();                                                           \
  } while (0)

    // prologue: stage tile 0 into buf 0; one-time full-latency drain.
    STAGE(0, 0);
    __syncthreads();

    #pragma unroll 1
    for (int kt2 = 0; kt2 < NKT / 2 - 1; ++kt2) {
        STEP(0, 2 * kt2, true);
        STEP(1, 2 * kt2 + 1, true);
    }
    STEP(0, NKT - 2, true);
    STEP(1, NKT - 1, false);

    // ---- epilogue: + b_gemm, GroupNorm over 128-col groups, group-min ----
    // C/D layout (verified m89/m91): col = lane&15, row = (lane>>4)*4 + reg.
    // Wave covers 64 cols = half a group; partner wave is wc^1. Exchange
    // (sum, sumsq) then per-row mins through LDS scratch. Scratch = lA[0],
    // last read in step NKT-2 which ended with __syncthreads; final step read
    // only buf 1 — no hazard.
    float bgv[4], gv[4], bv[4];
    #pragma unroll
    for (int nt = 0; nt < 4; ++nt) {
        int cg = n0 + wc * 64 + nt * 16 + r;
        bgv[nt] = bg[cg];
        gv[nt]  = gamma[cg];
        bv[nt]  = beta[cg];
    }

    float* sc1 = (float*)&lA[0][0];   // [2 wr][128 row][4 wc][2] = 8 KiB
    float* sc2 = sc1 + 2048;          // [2 wr][128 row][4 wc]    = 4 KiB

    // stage 1: per-row partial (sum, sumsq) over this wave's 64 cols
    #pragma unroll
    for (int mt = 0; mt < 8; ++mt) {
        #pragma unroll
        for (int reg = 0; reg < 4; ++reg) {
            int rowH = mt * 16 + quad * 4 + reg;     // 0..127 within wr half
            float s = 0.f, ss = 0.f;
            #pragma unroll
            for (int nt = 0; nt < 4; ++nt) {
                float y = acc[mt][nt][reg] + bgv[nt];
                s += y;
                ss += y * y;
            }
            #pragma unroll
            for (int d = 1; d < 16; d <<= 1) {       // reduce 16 lanes of quad
                s  += __shfl_xor(s,  d, 64);
                ss += __shfl_xor(ss, d, 64);
            }
            if (r == 0) {
                int idx = ((wr * 128 + rowH) * 4 + wc) * 2;
                sc1[idx] = s;
                sc1[idx + 1] = ss;
            }
        }
    }
    __syncthreads();

    // stage 2: full-group stats (own + partner), normalize, per-wave min
    #pragma unroll
    for (int mt = 0; mt < 8; ++mt) {
        #pragma unroll
        for (int reg = 0; reg < 4; ++reg) {
            int rowH = mt * 16 + quad * 4 + reg;
            int ib = (wr * 128 + rowH) * 4;
            float s  = sc1[(ib + wc) * 2]     + sc1[(ib + (wc ^ 1)) * 2];
            float ss = sc1[(ib + wc) * 2 + 1] + sc1[(ib + (wc ^ 1)) * 2 + 1];
            float mean = s * (1.0f / 128.0f);
            float var  = ss * (1.0f / 128.0f) - mean * mean;
            float rstd = rsqrtf(var + EPSV);
            float mn = 1e30f;
            #pragma unroll
            for (int nt = 0; nt < 4; ++nt) {
                float y = acc[mt][nt][reg] + bgv[nt];
                float z = (y - mean) * rstd * gv[nt] + bv[nt];
                mn = fminf(mn, z);
            }
            #pragma unroll
            for (int d = 1; d < 16; d <<= 1)
                mn = fminf(mn, __shfl_xor(mn, d, 64));
            if (r == 0) sc2[ib + wc] = mn;
        }
    }
    __syncthreads();

    // stage 3: combine the two waves of each group, write gmin
    if ((wc & 1) == 0 && r == 0) {
        #pragma unroll
        for (int mt = 0; mt < 8; ++mt) {
            #pragma unroll
            for (int reg = 0; reg < 4; ++reg) {
                int rowH = mt * 16 + quad * 4 + reg;
                int ib = (wr * 128 + rowH) * 4;
                float mn = fminf(sc2[ib + wc], sc2[ib + wc + 1]);
                int R = m0 + wr * 128 + rowH;
                gmin[(size_t)R * NGROUP + blockIdx.y * 2 + (wc >> 1)] = mn;
            }
        }
    }
#undef STAGE
#undef COMPUTE
#undef STEP
}

// ---------------- kernel 3: rowmin over groups + broadcast bias ----------------
__global__ __launch_bounds__(256) void finalize(
    const float* __restrict__ gmin, const float* __restrict__ bias,
    float* __restrict__ out)
{
    const int m = blockIdx.x;
    const int t = threadIdx.x;
    float v = gmin[(size_t)m * NGROUP + (t & 31)];
    #pragma unroll
    for (int d = 1; d < 32; d <<= 1)
        v = fminf(v, __shfl_xor(v, d, 64));
    float4* out4 = (float4*)(out + (size_t)m * N_DIM);
    const float4* bias4 = (const float4*)bias;
    for (int i = t; i < N_DIM / 4; i += 256) {
        float4 b = bias4[i];
        out4[i] = make_float4(v + b.x, v + b.y, v + b.z, v + b.w);
    }
}

extern "C" void kernel_launch(void* const* d_in, const int* in_sizes, int n_in,
                              void* d_out, int out_size, void* d_ws, size_t ws_size,
                              hipStream_t stream)
{
    const float* x     = (const float*)d_in[0];
    const float* W     = (const float*)d_in[1];
    const float* bg    = (const float*)d_in[2];
    const float* gamma = (const float*)d_in[3];
    const float* beta  = (const float*)d_in[4];
    const float* bias  = (const float*)d_in[5];
    float* out = (float*)d_out;

    // ws layout: xb (32 MiB bf16) | wb (16 MiB bf16) | gmin (1 MiB fp32)
    __bf16* xb = (__bf16*)d_ws;
    __bf16* wb = xb + (size_t)M_DIM * K_DIM;
    float* gmin = (float*)(wb + (size_t)N_DIM * K_DIM);

    size_t ntot8 = ((size_t)M_DIM * K_DIM + (size_t)N_DIM * K_DIM) / 8;
    int cvt_blocks = (int)((ntot8 + 255) / 256);
    convert_bf16<<<cvt_blocks, 256, 0, stream>>>(x, W, xb, wb);

    dim3 grid(M_DIM / 256, N_DIM / 256);
    gemm_gn_min<<<grid, 512, 0, stream>>>(xb, wb, bg, gamma, beta, gmin);

    finalize<<<M_DIM, 256, 0, stream>>>(gmin, bias, out);
}

// Round 5
// 353.769 us; speedup vs baseline: 1.0296x; 1.0037x over previous
//
#include <hip/hip_runtime.h>
#include <hip/hip_bf16.h>

#define M_DIM 8192
#define K_DIM 2048
#define N_DIM 4096
#define NGROUP 32
#define EPSV 1e-5f
#define NKS (K_DIM / 32)   // 64 K-steps of BK=32

typedef __bf16 bf16x8 __attribute__((ext_vector_type(8)));
typedef float floatx4 __attribute__((ext_vector_type(4)));

__device__ __forceinline__ void g2lds16(const void* g, void* l) {
    __builtin_amdgcn_global_load_lds(
        (__attribute__((address_space(1))) void*)(uintptr_t)g,
        (__attribute__((address_space(3))) void*)(uint32_t)(uintptr_t)l,
        16, 0, 0);
}

// ---------------- kernel 1: fp32 -> bf16 cast of x and W ----------------
__global__ __launch_bounds__(256) void convert_bf16(
    const float* __restrict__ x, const float* __restrict__ w,
    __bf16* __restrict__ xb, __bf16* __restrict__ wb)
{
    const size_t nx = (size_t)M_DIM * K_DIM / 8;
    const size_t nw = (size_t)N_DIM * K_DIM / 8;
    size_t i = (size_t)blockIdx.x * 256 + threadIdx.x;
    const float4* src;
    bf16x8* dst;
    size_t j;
    if (i < nx) { src = (const float4*)x; dst = (bf16x8*)xb; j = i; }
    else if (i < nx + nw) { src = (const float4*)w; dst = (bf16x8*)wb; j = i - nx; }
    else return;
    float4 a = src[j * 2];
    float4 b = src[j * 2 + 1];
    bf16x8 o = { (__bf16)a.x, (__bf16)a.y, (__bf16)a.z, (__bf16)a.w,
                 (__bf16)b.x, (__bf16)b.y, (__bf16)b.z, (__bf16)b.w };
    dst[j] = o;
}

// ---- kernel 2: R9 = R4 geometry + BK=32 double-buffer (48 KiB, 2 blocks/CU) ----
// Theory: R4's only structural stall is the staging drain (stage -> vmcnt(0)
// -> compute, issue->wait distance ~0). R8 proved the dbuf-1-barrier schedule
// is correct but died at 1 block/CU. R9 keeps R4's co-residency (LDS 48 KiB:
// 2 x (256+128) x 32 x 2B) AND the dbuf schedule: stage k+1 BEFORE computing
// k, one __syncthreads per K-step (64 barriers total, same as R4), drain only
// ever waits on loads issued a full compute-phase (~800+ cyc) earlier.
//
// BK=32 LDS layout (row-pair interleave, conflict-free, staging-linear):
// two 32-elem rows share a 128 B line; 16B slot index
//   pos = (row&1)*4 + (c ^ ((row>>1)&3)),  c = k-chunk 0..3.
// Staging thread t, round j covers (row0 = 2*(t>>3) + ((t>>2)&1) + j*64,
// c = (t&3) ^ ((t>>3)&3)); its slot works out to exactly t&7, so the LDS
// dest is the LINEAR address j*2048 + t*8 elems (wave-uniform base +
// lane x 16B, as global_load_lds requires). Reads spread 64 lanes over the
// 8 slot windows x 8 distinct lines — isomorphic to R4's measured-0-conflict
// pattern. Epilogue is R4's verbatim (BN=128 = one group, in-wave stats).
__global__ __launch_bounds__(256, 2) void gemm_gn_min(
    const __bf16* __restrict__ xb, const __bf16* __restrict__ wb,
    const float* __restrict__ bg, const float* __restrict__ gamma,
    const float* __restrict__ beta, float* __restrict__ gmin)
{
    __shared__ __bf16 lA[2][256 * 32];   // 16 KiB x2
    __shared__ __bf16 lB[2][128 * 32];   // 8 KiB x2

    const int t = threadIdx.x;
    const int m0 = blockIdx.x * 256;
    const int n0 = blockIdx.y * 128;
    const int w = t >> 6;        // wave 0..3; owns rows [w*64, w*64+64)
    const int l = t & 63;
    const int quad = l >> 4;
    const int r = l & 15;

    // staging: thread t covers (row0 + j*64, chunk cA) -> linear dest t*8+j*2048
    const int row0 = 2 * (t >> 3) + ((t >> 2) & 1);
    const int cST  = (t & 3) ^ ((t >> 3) & 3);
    const __bf16* gA = xb + (size_t)(m0 + row0) * K_DIM + cST * 8;
    const __bf16* gB = wb + (size_t)(n0 + row0) * K_DIM + cST * 8;

    // fragment read offset (lane-constant): line (r>>1), slot (r&1)*4 + (q^((r>>1)&3))
    const int laneA = ((r >> 1) * 64 +
                       (((r & 1) * 4) + (quad ^ ((r >> 1) & 3))) * 8);

    floatx4 acc[4][8];
    #pragma unroll
    for (int i = 0; i < 4; ++i)
        #pragma unroll
        for (int j = 0; j < 8; ++j)
            acc[i][j] = (floatx4){0.f, 0.f, 0.f, 0.f};

#define STAGE(BUF, K0)                                                         \
  do {                                                                         \
    _Pragma("unroll")                                                          \
    for (int j_ = 0; j_ < 4; ++j_)   /* A: 256 rows, 4 rounds of 64 */         \
      g2lds16(gA + (K0) + (size_t)(j_ * 64) * K_DIM,                           \
              (void*)&lA[BUF][j_ * 2048 + t * 8]);                             \
    _Pragma("unroll")                                                          \
    for (int j_ = 0; j_ < 2; ++j_)   /* B: 128 rows, 2 rounds of 64 */         \
      g2lds16(gB + (K0) + (size_t)(j_ * 64) * K_DIM,                           \
              (void*)&lB[BUF][j_ * 2048 + t * 8]);                             \
  } while (0)

#define COMPUTE(C)                                                             \
  do {                                                                         \
    bf16x8 af[4], bfv[8];                                                      \
    _Pragma("unroll")                                                          \
    for (int mt = 0; mt < 4; ++mt)                                             \
      af[mt] = *(const bf16x8*)&lA[C][w * 2048 + mt * 512 + laneA];            \
    _Pragma("unroll")                                                          \
    for (int nt = 0; nt < 8; ++nt)                                             \
      bfv[nt] = *(const bf16x8*)&lB[C][nt * 512 + laneA];                      \
    _Pragma("unroll")                                                          \
    for (int mt = 0; mt < 4; ++mt)                                             \
      _Pragma("unroll")                                                        \
      for (int nt = 0; nt < 8; ++nt)                                           \
        acc[mt][nt] = __builtin_amdgcn_mfma_f32_16x16x32_bf16(                 \
            af[mt], bfv[nt], acc[mt][nt], 0, 0, 0);                            \
  } while (0)

// One K-step: prefetch next tile into the other buffer, compute current,
// single barrier. The implicit vmcnt(0) drain waits only on loads issued
// one full compute-phase earlier.
#define STEP(C, KS, PF)                                                        \
  do {                                                                         \
    if (PF) STAGE(1 - (C), ((KS) + 1) * 32);                                   \
    COMPUTE(C);                                                                \
    __syncthreads();                                                           \
  } while (0)

    // prologue: stage step 0 into buf 0; one-time full-latency drain.
    STAGE(0, 0);
    __syncthreads();

    #pragma unroll 1
    for (int ks2 = 0; ks2 < NKS / 2 - 1; ++ks2) {
        STEP(0, 2 * ks2, true);
        STEP(1, 2 * ks2 + 1, true);
    }
    STEP(0, NKS - 2, true);
    STEP(1, NKS - 1, false);

    // ---- epilogue (R4 verbatim): + b_gemm, GroupNorm over 128 cols, min ----
    // C/D layout (verified m89/m91): col = lane&15, row = (lane>>4)*4 + reg.
    float bgv[8], gv[8], bv[8];
    #pragma unroll
    for (int nt = 0; nt < 8; ++nt) {
        int c = n0 + nt * 16 + r;
        bgv[nt] = bg[c];
        gv[nt]  = gamma[c];
        bv[nt]  = beta[c];
    }

    #pragma unroll
    for (int mt = 0; mt < 4; ++mt) {
        #pragma unroll
        for (int reg = 0; reg < 4; ++reg) {
            float yv[8];
            float s = 0.f, ss = 0.f;
            #pragma unroll
            for (int nt = 0; nt < 8; ++nt) {
                float y = acc[mt][nt][reg] + bgv[nt];
                yv[nt] = y;
                s += y;
                ss += y * y;
            }
            // reduce across the 16 lanes of this quad (cols nt*16+r = all 128)
            #pragma unroll
            for (int d = 1; d < 16; d <<= 1) {
                s  += __shfl_xor(s,  d, 64);
                ss += __shfl_xor(ss, d, 64);
            }
            float mean = s * (1.0f / 128.0f);
            float var  = ss * (1.0f / 128.0f) - mean * mean;
            float rstd = rsqrtf(var + EPSV);
            float mn = 1e30f;
            #pragma unroll
            for (int nt = 0; nt < 8; ++nt) {
                float z = (yv[nt] - mean) * rstd * gv[nt] + bv[nt];
                mn = fminf(mn, z);
            }
            #pragma unroll
            for (int d = 1; d < 16; d <<= 1)
                mn = fminf(mn, __shfl_xor(mn, d, 64));
            if (r == 0) {
                int R = m0 + w * 64 + mt * 16 + quad * 4 + reg;
                gmin[(size_t)R * NGROUP + blockIdx.y] = mn;
            }
        }
    }
#undef STAGE
#undef COMPUTE
#undef STEP
}

// ---------------- kernel 3: rowmin over groups + broadcast bias ----------------
__global__ __launch_bounds__(256) void finalize(
    const float* __restrict__ gmin, const float* __restrict__ bias,
    float* __restrict__ out)
{
    const int m = blockIdx.x;
    const int t = threadIdx.x;
    float v = gmin[(size_t)m * NGROUP + (t & 31)];
    #pragma unroll
    for (int d = 1; d < 32; d <<= 1)
        v = fminf(v, __shfl_xor(v, d, 64));
    float4* out4 = (float4*)(out + (size_t)m * N_DIM);
    const float4* bias4 = (const float4*)bias;
    for (int i = t; i < N_DIM / 4; i += 256) {
        float4 b = bias4[i];
        out4[i] = make_float4(v + b.x, v + b.y, v + b.z, v + b.w);
    }
}

extern "C" void kernel_launch(void* const* d_in, const int* in_sizes, int n_in,
                              void* d_out, int out_size, void* d_ws, size_t ws_size,
                              hipStream_t stream)
{
    const float* x     = (const float*)d_in[0];
    const float* W     = (const float*)d_in[1];
    const float* bg    = (const float*)d_in[2];
    const float* gamma = (const float*)d_in[3];
    const float* beta  = (const float*)d_in[4];
    const float* bias  = (const float*)d_in[5];
    float* out = (float*)d_out;

    // ws layout: xb (32 MiB bf16) | wb (16 MiB bf16) | gmin (1 MiB fp32)
    __bf16* xb = (__bf16*)d_ws;
    __bf16* wb = xb + (size_t)M_DIM * K_DIM;
    float* gmin = (float*)(wb + (size_t)N_DIM * K_DIM);

    size_t ntot8 = ((size_t)M_DIM * K_DIM + (size_t)N_DIM * K_DIM) / 8;
    int cvt_blocks = (int)((ntot8 + 255) / 256);
    convert_bf16<<<cvt_blocks, 256, 0, stream>>>(x, W, xb, wb);

    dim3 grid(M_DIM / 256, N_DIM / 128);
    gemm_gn_min<<<grid, 256, 0, stream>>>(xb, wb, bg, gamma, beta, gmin);

    finalize<<<M_DIM, 256, 0, stream>>>(gmin, bias, out);
}